// Round 11
// baseline (131.927 us; speedup 1.0000x reference)
//
#include <hip/hip_runtime.h>
#include <hip/hip_bf16.h>

// LFA_self — 3-kernel pipeline for MI355X (round 11).
// scores = Xq (Wq Wk^T) Xk^T + g(t2); out = attn . (Xv (Wv Wo)) + (bv Wo + bo).
// Round-11: W_DECL is PINNED into VGPRs via asm (r10's VGPR=72 proved the
// compiler kept W in LDS and re-read ~112 ds_read_b128/thread in the unit
// loop -> ~36us/CU of LDS-pipe serialization, the hidden wall). Also preload
// thread-invariant wkbq/bvo scalars. Everything else identical to r10.

#define NT 49
#define TOKS 16384
#define HSL 1024
#define SLOT 3200            // floats per partial slot: 49x64 scores + 64 g-tail
#define ZSWZ(n) (((((n) & 7) ^ (((n) >> 3) & 7))) << 4)

typedef __attribute__((ext_vector_type(8))) short bf16x8;
typedef __attribute__((ext_vector_type(4))) float f32x4;

__device__ __forceinline__ ushort f2bf(float f) {
    union { float f; unsigned u; } v; v.f = f;
    return (ushort)((v.u + 0x7fffu + ((v.u >> 16) & 1u)) >> 16);   // RNE
}
__device__ __forceinline__ unsigned pk2(float lo, float hi) {
    return (unsigned)f2bf(lo) | ((unsigned)f2bf(hi) << 16);
}
// 16-term dot: x (16 ch as 4 f32x4) . w-row (4 f32x4)
__device__ __forceinline__ float qdot(f32x4 x0, f32x4 x1, f32x4 x2, f32x4 x3,
                                      f32x4 wa, f32x4 wb, f32x4 wc, f32x4 wd) {
    float s =      x0[0]*wa[0];
    s = fmaf(x0[1], wa[1], s); s = fmaf(x0[2], wa[2], s); s = fmaf(x0[3], wa[3], s);
    s = fmaf(x1[0], wb[0], s); s = fmaf(x1[1], wb[1], s); s = fmaf(x1[2], wb[2], s);
    s = fmaf(x1[3], wb[3], s);
    s = fmaf(x2[0], wc[0], s); s = fmaf(x2[1], wc[1], s); s = fmaf(x2[2], wc[2], s);
    s = fmaf(x2[3], wc[3], s);
    s = fmaf(x3[0], wd[0], s); s = fmaf(x3[1], wd[1], s); s = fmaf(x3[2], wd[2], s);
    s = fmaf(x3[3], wd[3], s);
    return s;
}

// W preload: 16 named f32x4 = 4 rows (c2 = 4rq..4rq+3) of transposed 16x16 W
#define W_DECL(mb) \
    f32x4 W00 = *(const f32x4*)((mb)+ 0), W01 = *(const f32x4*)((mb)+ 4), \
          W02 = *(const f32x4*)((mb)+ 8), W03 = *(const f32x4*)((mb)+12), \
          W10 = *(const f32x4*)((mb)+16), W11 = *(const f32x4*)((mb)+20), \
          W12 = *(const f32x4*)((mb)+24), W13 = *(const f32x4*)((mb)+28), \
          W20 = *(const f32x4*)((mb)+32), W21 = *(const f32x4*)((mb)+36), \
          W22 = *(const f32x4*)((mb)+40), W23 = *(const f32x4*)((mb)+44), \
          W30 = *(const f32x4*)((mb)+48), W31 = *(const f32x4*)((mb)+52), \
          W32 = *(const f32x4*)((mb)+56), W33 = *(const f32x4*)((mb)+60)

// Force materialization in VGPRs (compiler otherwise re-reads LDS per use)
#define W_PIN() asm volatile("" : \
    "+v"(W00), "+v"(W01), "+v"(W02), "+v"(W03), \
    "+v"(W10), "+v"(W11), "+v"(W12), "+v"(W13), \
    "+v"(W20), "+v"(W21), "+v"(W22), "+v"(W23), \
    "+v"(W30), "+v"(W31), "+v"(W32), "+v"(W33))

// ===== K1: partial scores, grid (b,h,s)=512*SPLIT, 256 thr =================
template<int SPLIT, int LOG2S>
__global__ __launch_bounds__(256, 2) void k_scores(
    const float* __restrict__ qin, const float* __restrict__ kin,
    const float* __restrict__ Wq, const float* __restrict__ bq,
    const float* __restrict__ Wk, float* __restrict__ ws1)
{
    __shared__ ushort bufA[64*128];   // Yq bf16, 256B rows, XOR-swizzled
    __shared__ ushort bufB[64*128];   // Xk bf16, swizzled
    __shared__ float  Msh[256];       // (Wq Wk^T)^T : Msh[c2*16+c1]
    __shared__ float  wkbqSh[16];     // Wk bq
    __shared__ float  gSh[64];

    const int tid  = threadIdx.x;
    const int lane = tid & 63;
    const int wv   = tid >> 6;        // 0..3
    const int s    = blockIdx.x & (SPLIT - 1);
    const int h    = (blockIdx.x >> LOG2S) & 15;
    const int b    = blockIdx.x >> (LOG2S + 4);

    const float* qbase = qin + (size_t)b*NT*TOKS + h*HSL + s*(1024/SPLIT);
    const float* kbase = kin + (size_t)b*NT*TOKS + h*HSL + s*(1024/SPLIT);

    const int f4 = tid & 31;          // k-item column group (invariant)
    const int t0 = tid >> 5;          // base token
    const int si = (tid >> 2) & 7;    // q-unit column group (invariant)
    const int rq = tid & 3;           // q-unit output quarter (invariant)

    constexpr int NC = 8 / SPLIT;

    // ---- issue chunk-0 loads FIRST (latency hides under init)
    f32x4 kv[7];
    {
        const float* kp = kbase + f4*4;
        #pragma unroll
        for (int i = 0; i < 7; ++i) {
            const int t = t0 + 8*i; const int tc = t < 48 ? t : 48;
            kv[i] = *(const f32x4*)(kp + (size_t)tc*TOKS);
        }
    }
    f32x4 xa0, xa1, xa2, xa3;
    {
        const float* qc = qbase + si*16 + (size_t)t0*TOKS;
        xa0 = *(const f32x4*)(qc);
        xa1 = *(const f32x4*)(qc + 4);
        xa2 = *(const f32x4*)(qc + 8);
        xa3 = *(const f32x4*)(qc + 12);
    }

    {   // init: zero both MFMA buffers (pad rows 49..63 must be 0), weights
        unsigned* z0 = (unsigned*)bufA; unsigned* z1 = (unsigned*)bufB;
        #pragma unroll
        for (int i = 0; i < 16; ++i) { z0[tid + 256*i] = 0u; z1[tid + 256*i] = 0u; }
        const int c1 = tid >> 4, c2 = tid & 15;
        float m = 0.f;
        #pragma unroll
        for (int f = 0; f < 16; ++f) m += Wq[c1*16+f] * Wk[c2*16+f];
        Msh[c2*16 + c1] = m;                       // transposed store
        if (tid < 16) {
            float wb = 0.f;
            #pragma unroll
            for (int g = 0; g < 16; ++g) wb += Wk[tid*16+g] * bq[g];
            wkbqSh[tid] = wb;
        }
        if (tid < 64) gSh[tid] = 0.f;
    }
    __syncthreads();

    W_DECL(Msh + rq*64);              // this lane's 4 output rows of M^T
    W_PIN();                          // keep in VGPRs — no LDS re-reads
    f32x4 wkb = *(const f32x4*)(wkbqSh + (f4 & 3)*4);   // invariant preload

    f32x4 accS[4];
    #pragma unroll
    for (int nt = 0; nt < 4; ++nt) accS[nt] = (f32x4){0.f,0.f,0.f,0.f};

    for (int kc = 0; kc < NC; ++kc) {
        if (kc > 0) {                 // fallback paths (SPLIT<8): refill batches
            const float* kp = kbase + kc*128 + f4*4;
            #pragma unroll
            for (int i = 0; i < 7; ++i) {
                const int t = t0 + 8*i; const int tc = t < 48 ? t : 48;
                kv[i] = *(const f32x4*)(kp + (size_t)tc*TOKS);
            }
            const float* qc = qbase + kc*128 + si*16 + (size_t)t0*TOKS;
            xa0 = *(const f32x4*)(qc);
            xa1 = *(const f32x4*)(qc + 4);
            xa2 = *(const f32x4*)(qc + 8);
            xa3 = *(const f32x4*)(qc + 12);
        }
        // ---- k: convert + write bufB (overlaps q-unit-0 latency)
        #pragma unroll
        for (int i = 0; i < 7; ++i) {
            const int t = t0 + 8*i;
            f32x4 xk = kv[i];
            if (t >= NT) xk = (f32x4){0.f,0.f,0.f,0.f};
            uint2 w; w.x = pk2(xk[0], xk[1]); w.y = pk2(xk[2], xk[3]);
            *(uint2*)((char*)bufB + ((t*256 + f4*8) ^ ((t & 7) << 4))) = w;
            const float pg = xk[0]*wkb[0] + xk[1]*wkb[1] + xk[2]*wkb[2] + xk[3]*wkb[3];
            if (pg != 0.f) atomicAdd(&gSh[t], pg);   // bq==0 -> never fires
        }
        // ---- q units: 2-deep pipeline {load next, project current}
        #pragma unroll
        for (int i = 0; i < 7; ++i) {
            f32x4 xb0 = xa0, xb1 = xa1, xb2 = xa2, xb3 = xa3;
            if (i < 6) {
                const int tn = t0 + 8*(i+1); const int tc = tn < 48 ? tn : 48;
                const float* qc = qbase + kc*128 + si*16 + (size_t)tc*TOKS;
                xb0 = *(const f32x4*)(qc);
                xb1 = *(const f32x4*)(qc + 4);
                xb2 = *(const f32x4*)(qc + 8);
                xb3 = *(const f32x4*)(qc + 12);
            }
            const int t = t0 + 8*i;
            if (t < NT) {
                const float o0 = qdot(xa0,xa1,xa2,xa3, W00,W01,W02,W03);
                const float o1 = qdot(xa0,xa1,xa2,xa3, W10,W11,W12,W13);
                const float o2 = qdot(xa0,xa1,xa2,xa3, W20,W21,W22,W23);
                const float o3 = qdot(xa0,xa1,xa2,xa3, W30,W31,W32,W33);
                uint2 w; w.x = pk2(o0, o1); w.y = pk2(o2, o3);
                *(uint2*)((char*)bufA + ((t*256 + si*32 + rq*8) ^ ((t & 7) << 4))) = w;
            }
            xa0 = xb0; xa1 = xb1; xa2 = xb2; xa3 = xb3;
        }
        __syncthreads();
        // ---- MFMA: K-chunk 128 = 4 ksteps (proven path, unchanged)
        #pragma unroll
        for (int ks = 0; ks < 4; ++ks) {
            const int ra  = wv*16 + (lane & 15);
            const int abo = (ra*256 + (ks*32 + (lane >> 4)*8)*2) ^ ((ra & 7) << 4);
            const bf16x8 af = *(const bf16x8*)((const char*)bufA + abo);
            #pragma unroll
            for (int nt = 0; nt < 4; ++nt) {
                const int rb  = nt*16 + (lane & 15);
                const int bbo = (rb*256 + (ks*32 + (lane >> 4)*8)*2) ^ ((rb & 7) << 4);
                const bf16x8 bf = *(const bf16x8*)((const char*)bufB + bbo);
                accS[nt] = __builtin_amdgcn_mfma_f32_16x16x32_bf16(af, bf, accS[nt], 0, 0, 0);
            }
        }
        if (kc + 1 < NC) __syncthreads();
    }

    float* slot = ws1 + (size_t)blockIdx.x * SLOT;
    #pragma unroll
    for (int nt = 0; nt < 4; ++nt) {
        const int col = nt*16 + (lane & 15);
        #pragma unroll
        for (int rr = 0; rr < 4; ++rr) {
            const int row = wv*16 + (lane >> 4)*4 + rr;
            if (row < NT) slot[row*64 + col] = accS[nt][rr];
        }
    }
    if (tid < 64) slot[3136 + tid] = gSh[tid];
}

// ===== K2: reduce + softmax, grid (b,h)=512, 256 thr =======================
template<int SPLIT>
__global__ __launch_bounds__(256, 2) void k_softmax(
    const float* __restrict__ ws1, float* __restrict__ attnp,
    ushort* __restrict__ ws2)
{
    __shared__ float sS[NT*69];
    __shared__ float sG[64];
    const int tid = threadIdx.x;
    const float* base = ws1 + (size_t)blockIdx.x * SPLIT * SLOT;

    for (int p = tid; p < 784; p += 256) {
        const int row = p >> 4, c4 = (p & 15) * 4;
        float4 acc = *(const float4*)(base + row*64 + c4);
        #pragma unroll
        for (int s = 1; s < SPLIT; ++s) {
            const float4 a = *(const float4*)(base + s*SLOT + row*64 + c4);
            acc.x += a.x; acc.y += a.y; acc.z += a.z; acc.w += a.w;
        }
        sS[row*69 + c4 + 0] = acc.x;
        sS[row*69 + c4 + 1] = acc.y;
        sS[row*69 + c4 + 2] = acc.z;
        sS[row*69 + c4 + 3] = acc.w;
    }
    if (tid < 64) {
        float g = base[3136 + tid];
        #pragma unroll
        for (int s = 1; s < SPLIT; ++s) g += base[s*SLOT + 3136 + tid];
        sG[tid] = g;
    }
    __syncthreads();

    if (tid < NT) {
        float mx = -1e30f;
        for (int j = 0; j < NT; ++j) {
            const float v = (sS[tid*69 + j] + sG[j]) * 0.03125f;
            sS[tid*69 + j] = v;
            mx = fmaxf(mx, v);
        }
        float ssum = 0.f;
        for (int j = 0; j < NT; ++j) {
            const float e = __expf(sS[tid*69 + j] - mx);
            sS[tid*69 + j] = e; ssum += e;
        }
        const float inv = 1.0f / ssum;
        for (int j = 0; j < NT; ++j) sS[tid*69 + j] *= inv;
    }
    __syncthreads();

    float* ab = attnp + (size_t)blockIdx.x * (NT*NT);
    for (int p = tid; p < NT*NT; p += 256) {
        const int t = p / NT, j = p - t*NT;
        ab[p] = sS[t*69 + j];
    }
    ushort* w2 = ws2 + (size_t)blockIdx.x * 4096;   // 64x64 bf16, zero-padded
    for (int p = tid; p < 4096; p += 256) {
        const int t = p >> 6, j = p & 63;
        const float v = (t < NT && j < NT) ? sS[t*69 + j] : 0.f;
        w2[p] = f2bf(v);
    }
}

// ===== K3: out = attn.Z + bvo, grid (b,h,kc)=4096, 256 thr =================
__global__ __launch_bounds__(256, 2) void k_out(
    const float* __restrict__ vin,
    const float* __restrict__ Wv, const float* __restrict__ bv,
    const float* __restrict__ Wo, const float* __restrict__ bo,
    const ushort* __restrict__ ws2, float* __restrict__ out)
{
    __shared__ unsigned Zt[4096];     // Z^T pair-packed: [128 n][32 kpair] u32
    __shared__ float WvoSh[256];      // (Wv Wo)^T
    __shared__ float bvoSh[16];

    const int tid  = threadIdx.x;
    const int lane = tid & 63;
    const int wv   = tid >> 6;        // 0..3 -> M-tile (token rows)
    const int kc   = blockIdx.x & 7;
    const int h    = (blockIdx.x >> 3) & 15;
    const int b    = blockIdx.x >> 7;
    const float* vbase = vin + (size_t)b*NT*TOKS + h*HSL;

    const int si = (tid >> 2) & 7;    // unit column group (invariant)
    const int rq = tid & 3;           // unit output quarter (invariant)
    const int t0 = tid >> 5;          // base token

    // ---- issue global loads first (attn A-fragments + v unit 0)
    const ushort* w2 = ws2 + ((size_t)(blockIdx.x >> 3)) * 4096;
    const int ra = wv*16 + (lane & 15);
    const bf16x8 af0 = *(const bf16x8*)(w2 + ra*64 +      (lane >> 4)*8);
    const bf16x8 af1 = *(const bf16x8*)(w2 + ra*64 + 32 + (lane >> 4)*8);
    f32x4 xa0, xa1, xa2, xa3;
    {
        const float* vc = vbase + kc*128 + si*16 + (size_t)t0*TOKS;
        xa0 = *(const f32x4*)(vc);
        xa1 = *(const f32x4*)(vc + 4);
        xa2 = *(const f32x4*)(vc + 8);
        xa3 = *(const f32x4*)(vc + 12);
    }

    {   // init: weights (transposed), bias, full Zt zero (covers t=49.. pad)
        const int c1 = tid >> 4, c2 = tid & 15;
        float wvo = 0.f;
        #pragma unroll
        for (int f = 0; f < 16; ++f) wvo += Wv[c1*16+f] * Wo[f*16+c2];
        WvoSh[c2*16 + c1] = wvo;                  // transposed store
        if (tid < 16) {
            float s2 = 0.f;
            #pragma unroll
            for (int g = 0; g < 16; ++g) s2 += bv[g]*Wo[g*16+tid];
            bvoSh[tid] = s2 + bo[tid];
        }
        #pragma unroll
        for (int i = 0; i < 16; ++i) Zt[tid + 256*i] = 0u;
    }
    __syncthreads();

    W_DECL(WvoSh + rq*64);
    W_PIN();                          // keep in VGPRs — no LDS re-reads
    const float bias = bvoSh[lane & 15];   // invariant: (n & 15) == lane & 15

    // ---- units: {load next, project current, 4 u16 writes into Zt}
    #pragma unroll
    for (int i = 0; i < 7; ++i) {
        f32x4 xb0 = xa0, xb1 = xa1, xb2 = xa2, xb3 = xa3;
        if (i < 6) {
            const int tn = t0 + 8*(i+1); const int tc = tn < 48 ? tn : 48;
            const float* vc = vbase + kc*128 + si*16 + (size_t)tc*TOKS;
            xb0 = *(const f32x4*)(vc);
            xb1 = *(const f32x4*)(vc + 4);
            xb2 = *(const f32x4*)(vc + 8);
            xb3 = *(const f32x4*)(vc + 12);
        }
        const int t = t0 + 8*i;
        if (t < NT) {
            const float o0 = qdot(xa0,xa1,xa2,xa3, W00,W01,W02,W03);
            const float o1 = qdot(xa0,xa1,xa2,xa3, W10,W11,W12,W13);
            const float o2 = qdot(xa0,xa1,xa2,xa3, W20,W21,W22,W23);
            const float o3 = qdot(xa0,xa1,xa2,xa3, W30,W31,W32,W33);
            const int n0 = si*16 + rq*4;
            const int pb = (t >> 1)*4, hb = (t & 1)*2;
            *(ushort*)((char*)Zt + ((((n0+0)*128 + pb) ^ ZSWZ(n0+0)) + hb)) = f2bf(o0);
            *(ushort*)((char*)Zt + ((((n0+1)*128 + pb) ^ ZSWZ(n0+1)) + hb)) = f2bf(o1);
            *(ushort*)((char*)Zt + ((((n0+2)*128 + pb) ^ ZSWZ(n0+2)) + hb)) = f2bf(o2);
            *(ushort*)((char*)Zt + ((((n0+3)*128 + pb) ^ ZSWZ(n0+3)) + hb)) = f2bf(o3);
        }
        xa0 = xb0; xa1 = xb1; xa2 = xb2; xa3 = xb3;
    }
    __syncthreads();

    // MFMA + direct global store (4 rows x 64B full sectors per instruction)
    float* obase = out + (size_t)b*NT*TOKS + h*HSL + kc*128;
    #pragma unroll
    for (int nt2 = 0; nt2 < 8; ++nt2) {
        const int n    = nt2*16 + (lane & 15);
        const int swzn = ZSWZ(n);
        const bf16x8 bf0 = *(const bf16x8*)((const char*)Zt + ((n*128 +      (lane >> 4)*16) ^ swzn));
        const bf16x8 bf1 = *(const bf16x8*)((const char*)Zt + ((n*128 + 64 + (lane >> 4)*16) ^ swzn));
        f32x4 acc = (f32x4){0.f, 0.f, 0.f, 0.f};
        acc = __builtin_amdgcn_mfma_f32_16x16x32_bf16(af0, bf0, acc, 0, 0, 0);
        acc = __builtin_amdgcn_mfma_f32_16x16x32_bf16(af1, bf1, acc, 0, 0, 0);
        #pragma unroll
        for (int r2 = 0; r2 < 4; ++r2) {
            const int row = wv*16 + (lane >> 4)*4 + r2;
            if (row < NT) obase[(size_t)row*TOKS + n] = acc[r2] + bias;
        }
    }
}

extern "C" void kernel_launch(void* const* d_in, const int* in_sizes, int n_in,
                              void* d_out, int out_size, void* d_ws, size_t ws_size,
                              hipStream_t stream) {
    const float* v  = (const float*)d_in[0];
    const float* k  = (const float*)d_in[1];
    const float* q  = (const float*)d_in[2];
    const float* Wq = (const float*)d_in[3];
    const float* bq = (const float*)d_in[4];
    const float* Wk = (const float*)d_in[5];
    const float* bk = (const float*)d_in[6];   // softmax-row-invariant; unused
    const float* Wv = (const float*)d_in[7];
    const float* bv = (const float*)d_in[8];
    const float* Wo = (const float*)d_in[9];
    const float* bo = (const float*)d_in[10];
    (void)bk; (void)in_sizes; (void)n_in; (void)out_size;

    float* outp  = (float*)d_out;
    float* attnp = outp + (size_t)32 * 49 * 16384;      // out | attn concat
    float* ws1   = (float*)d_ws;

    const size_t need8 = (size_t)4096*SLOT*4 + (size_t)512*4096*2;
    const size_t need4 = (size_t)2048*SLOT*4 + (size_t)512*4096*2;
    if (ws_size >= need8) {
        ushort* ws2 = (ushort*)(ws1 + (size_t)4096*SLOT);
        k_scores<8,3><<<dim3(4096), dim3(256), 0, stream>>>(q, k, Wq, bq, Wk, ws1);
        k_softmax<8> <<<dim3(512),  dim3(256), 0, stream>>>(ws1, attnp, ws2);
        k_out        <<<dim3(4096), dim3(256), 0, stream>>>(v, Wv, bv, Wo, bo, ws2, outp);
    } else if (ws_size >= need4) {
        ushort* ws2 = (ushort*)(ws1 + (size_t)2048*SLOT);
        k_scores<4,2><<<dim3(2048), dim3(256), 0, stream>>>(q, k, Wq, bq, Wk, ws1);
        k_softmax<4> <<<dim3(512),  dim3(256), 0, stream>>>(ws1, attnp, ws2);
        k_out        <<<dim3(4096), dim3(256), 0, stream>>>(v, Wv, bv, Wo, bo, ws2, outp);
    } else {
        ushort* ws2 = (ushort*)(ws1 + (size_t)1024*SLOT);
        k_scores<2,1><<<dim3(1024), dim3(256), 0, stream>>>(q, k, Wq, bq, Wk, ws1);
        k_softmax<2> <<<dim3(512),  dim3(256), 0, stream>>>(ws1, attnp, ws2);
        k_out        <<<dim3(4096), dim3(256), 0, stream>>>(v, Wv, bv, Wo, bo, ws2, outp);
    }
}

// Round 12
// 129.882 us; speedup vs baseline: 1.0157x; 1.0157x over previous
//
#include <hip/hip_runtime.h>
#include <hip/hip_bf16.h>

// LFA_self — 3-kernel pipeline for MI355X (round 12).
// scores = Xq (Wq Wk^T) Xk^T + g(t2); out = attn . (Xv (Wv Wo)) + (bv Wo + bo).
// Round-12: k_scores (SPLIT=8 path) issues ALL 35 global loads up-front and
// drains ONCE (k_out's proven single-drain discipline; r11 showed k_scores'
// 2-deep pipeline exposes ~6 congested-latency drains/block = the 29k-cycle
// wall). Fallback SPLIT<8 paths keep the r11 kernel. k_out/k_softmax frozen.

#define NT 49
#define TOKS 16384
#define HSL 1024
#define SLOT 3200            // floats per partial slot: 49x64 scores + 64 g-tail
#define ZSWZ(n) (((((n) & 7) ^ (((n) >> 3) & 7))) << 4)

typedef __attribute__((ext_vector_type(8))) short bf16x8;
typedef __attribute__((ext_vector_type(4))) float f32x4;

__device__ __forceinline__ ushort f2bf(float f) {
    union { float f; unsigned u; } v; v.f = f;
    return (ushort)((v.u + 0x7fffu + ((v.u >> 16) & 1u)) >> 16);   // RNE
}
__device__ __forceinline__ unsigned pk2(float lo, float hi) {
    return (unsigned)f2bf(lo) | ((unsigned)f2bf(hi) << 16);
}
// 16-term dot: x (16 ch as 4 f32x4) . w-row (4 f32x4)
__device__ __forceinline__ float qdot(f32x4 x0, f32x4 x1, f32x4 x2, f32x4 x3,
                                      f32x4 wa, f32x4 wb, f32x4 wc, f32x4 wd) {
    float s =      x0[0]*wa[0];
    s = fmaf(x0[1], wa[1], s); s = fmaf(x0[2], wa[2], s); s = fmaf(x0[3], wa[3], s);
    s = fmaf(x1[0], wb[0], s); s = fmaf(x1[1], wb[1], s); s = fmaf(x1[2], wb[2], s);
    s = fmaf(x1[3], wb[3], s);
    s = fmaf(x2[0], wc[0], s); s = fmaf(x2[1], wc[1], s); s = fmaf(x2[2], wc[2], s);
    s = fmaf(x2[3], wc[3], s);
    s = fmaf(x3[0], wd[0], s); s = fmaf(x3[1], wd[1], s); s = fmaf(x3[2], wd[2], s);
    s = fmaf(x3[3], wd[3], s);
    return s;
}

// W preload: 16 named f32x4 = 4 rows (c2 = 4rq..4rq+3) of transposed 16x16 W
#define W_DECL(mb) \
    f32x4 W00 = *(const f32x4*)((mb)+ 0), W01 = *(const f32x4*)((mb)+ 4), \
          W02 = *(const f32x4*)((mb)+ 8), W03 = *(const f32x4*)((mb)+12), \
          W10 = *(const f32x4*)((mb)+16), W11 = *(const f32x4*)((mb)+20), \
          W12 = *(const f32x4*)((mb)+24), W13 = *(const f32x4*)((mb)+28), \
          W20 = *(const f32x4*)((mb)+32), W21 = *(const f32x4*)((mb)+36), \
          W22 = *(const f32x4*)((mb)+40), W23 = *(const f32x4*)((mb)+44), \
          W30 = *(const f32x4*)((mb)+48), W31 = *(const f32x4*)((mb)+52), \
          W32 = *(const f32x4*)((mb)+56), W33 = *(const f32x4*)((mb)+60)

// ===== K1 (main): SPLIT=8, grid 4096, 256 thr — single-drain version ======
__global__ __launch_bounds__(256, 2) void k_scores8(
    const float* __restrict__ qin, const float* __restrict__ kin,
    const float* __restrict__ Wq, const float* __restrict__ bq,
    const float* __restrict__ Wk, float* __restrict__ ws1)
{
    __shared__ ushort bufA[64*128];   // Yq bf16, 256B rows, XOR-swizzled
    __shared__ ushort bufB[64*128];   // Xk bf16, swizzled
    __shared__ float  Msh[256];       // (Wq Wk^T)^T : Msh[c2*16+c1]
    __shared__ float  wkbqSh[16];     // Wk bq
    __shared__ float  gSh[64];

    const int tid  = threadIdx.x;
    const int lane = tid & 63;
    const int wv   = tid >> 6;        // 0..3
    const int s    = blockIdx.x & 7;
    const int h    = (blockIdx.x >> 3) & 15;
    const int b    = blockIdx.x >> 7;

    const float* qbase = qin + (size_t)b*NT*TOKS + h*HSL + s*128;
    const float* kbase = kin + (size_t)b*NT*TOKS + h*HSL + s*128;

    const int f4 = tid & 31;          // k-item column group (invariant)
    const int t0 = tid >> 5;          // base token
    const int si = (tid >> 2) & 7;    // q-unit column group (invariant)
    const int rq = tid & 3;           // q-unit output quarter (invariant)

    // ---- issue ALL 35 loads back-to-back; latency hides under init + drain
    f32x4 kv[7];
    {
        const float* kp = kbase + f4*4;
        #pragma unroll
        for (int i = 0; i < 7; ++i) {
            const int t = t0 + 8*i; const int tc = t < 48 ? t : 48;
            kv[i] = *(const f32x4*)(kp + (size_t)tc*TOKS);
        }
    }
    f32x4 q0[7], q1[7], q2[7], q3[7];
    {
        #pragma unroll
        for (int i = 0; i < 7; ++i) {
            const int t = t0 + 8*i; const int tc = t < 48 ? t : 48;
            const float* qc = qbase + si*16 + (size_t)tc*TOKS;
            q0[i] = *(const f32x4*)(qc);
            q1[i] = *(const f32x4*)(qc + 4);
            q2[i] = *(const f32x4*)(qc + 8);
            q3[i] = *(const f32x4*)(qc + 12);
        }
    }

    {   // init: zero both MFMA buffers (pad rows 49..63 must be 0), weights
        unsigned* z0 = (unsigned*)bufA; unsigned* z1 = (unsigned*)bufB;
        #pragma unroll
        for (int i = 0; i < 16; ++i) { z0[tid + 256*i] = 0u; z1[tid + 256*i] = 0u; }
        const int c1 = tid >> 4, c2 = tid & 15;
        float m = 0.f;
        #pragma unroll
        for (int f = 0; f < 16; ++f) m += Wq[c1*16+f] * Wk[c2*16+f];
        Msh[c2*16 + c1] = m;                       // transposed store
        if (tid < 16) {
            float wb = 0.f;
            #pragma unroll
            for (int g = 0; g < 16; ++g) wb += Wk[tid*16+g] * bq[g];
            wkbqSh[tid] = wb;
        }
        if (tid < 64) gSh[tid] = 0.f;
    }
    __syncthreads();

    W_DECL(Msh + rq*64);              // this lane's 4 output rows of M^T
    f32x4 wkb = *(const f32x4*)(wkbqSh + (f4 & 3)*4);

    // ---- k: convert + write bufB
    #pragma unroll
    for (int i = 0; i < 7; ++i) {
        const int t = t0 + 8*i;
        f32x4 xk = kv[i];
        if (t >= NT) xk = (f32x4){0.f,0.f,0.f,0.f};
        uint2 w; w.x = pk2(xk[0], xk[1]); w.y = pk2(xk[2], xk[3]);
        *(uint2*)((char*)bufB + ((t*256 + f4*8) ^ ((t & 7) << 4))) = w;
        const float pg = xk[0]*wkb[0] + xk[1]*wkb[1] + xk[2]*wkb[2] + xk[3]*wkb[3];
        if (pg != 0.f) atomicAdd(&gSh[t], pg);   // bq==0 -> never fires
    }
    // ---- q: project + write bufA
    #pragma unroll
    for (int i = 0; i < 7; ++i) {
        const int t = t0 + 8*i;
        if (t < NT) {
            const float o0 = qdot(q0[i],q1[i],q2[i],q3[i], W00,W01,W02,W03);
            const float o1 = qdot(q0[i],q1[i],q2[i],q3[i], W10,W11,W12,W13);
            const float o2 = qdot(q0[i],q1[i],q2[i],q3[i], W20,W21,W22,W23);
            const float o3 = qdot(q0[i],q1[i],q2[i],q3[i], W30,W31,W32,W33);
            uint2 w; w.x = pk2(o0, o1); w.y = pk2(o2, o3);
            *(uint2*)((char*)bufA + ((t*256 + si*32 + rq*8) ^ ((t & 7) << 4))) = w;
        }
    }
    __syncthreads();

    // ---- MFMA: K-chunk 128 = 4 ksteps (proven path, unchanged)
    f32x4 accS[4];
    #pragma unroll
    for (int nt = 0; nt < 4; ++nt) accS[nt] = (f32x4){0.f,0.f,0.f,0.f};
    #pragma unroll
    for (int ks = 0; ks < 4; ++ks) {
        const int ra  = wv*16 + (lane & 15);
        const int abo = (ra*256 + (ks*32 + (lane >> 4)*8)*2) ^ ((ra & 7) << 4);
        const bf16x8 af = *(const bf16x8*)((const char*)bufA + abo);
        #pragma unroll
        for (int nt = 0; nt < 4; ++nt) {
            const int rb  = nt*16 + (lane & 15);
            const int bbo = (rb*256 + (ks*32 + (lane >> 4)*8)*2) ^ ((rb & 7) << 4);
            const bf16x8 bf = *(const bf16x8*)((const char*)bufB + bbo);
            accS[nt] = __builtin_amdgcn_mfma_f32_16x16x32_bf16(af, bf, accS[nt], 0, 0, 0);
        }
    }

    float* slot = ws1 + (size_t)blockIdx.x * SLOT;
    #pragma unroll
    for (int nt = 0; nt < 4; ++nt) {
        const int col = nt*16 + (lane & 15);
        #pragma unroll
        for (int rr = 0; rr < 4; ++rr) {
            const int row = wv*16 + (lane >> 4)*4 + rr;
            if (row < NT) slot[row*64 + col] = accS[nt][rr];
        }
    }
    if (tid < 64) slot[3136 + tid] = gSh[tid];
}

// ===== K1 (fallback): generic SPLIT, r11 structure ========================
template<int SPLIT, int LOG2S>
__global__ __launch_bounds__(256, 2) void k_scores(
    const float* __restrict__ qin, const float* __restrict__ kin,
    const float* __restrict__ Wq, const float* __restrict__ bq,
    const float* __restrict__ Wk, float* __restrict__ ws1)
{
    __shared__ ushort bufA[64*128];
    __shared__ ushort bufB[64*128];
    __shared__ float  Msh[256];
    __shared__ float  wkbqSh[16];
    __shared__ float  gSh[64];

    const int tid  = threadIdx.x;
    const int lane = tid & 63;
    const int wv   = tid >> 6;
    const int s    = blockIdx.x & (SPLIT - 1);
    const int h    = (blockIdx.x >> LOG2S) & 15;
    const int b    = blockIdx.x >> (LOG2S + 4);

    const float* qbase = qin + (size_t)b*NT*TOKS + h*HSL + s*(1024/SPLIT);
    const float* kbase = kin + (size_t)b*NT*TOKS + h*HSL + s*(1024/SPLIT);

    const int f4 = tid & 31;
    const int t0 = tid >> 5;
    const int si = (tid >> 2) & 7;
    const int rq = tid & 3;

    constexpr int NC = 8 / SPLIT;

    f32x4 kv[7];
    {
        const float* kp = kbase + f4*4;
        #pragma unroll
        for (int i = 0; i < 7; ++i) {
            const int t = t0 + 8*i; const int tc = t < 48 ? t : 48;
            kv[i] = *(const f32x4*)(kp + (size_t)tc*TOKS);
        }
    }
    f32x4 xa0, xa1, xa2, xa3;
    {
        const float* qc = qbase + si*16 + (size_t)t0*TOKS;
        xa0 = *(const f32x4*)(qc);
        xa1 = *(const f32x4*)(qc + 4);
        xa2 = *(const f32x4*)(qc + 8);
        xa3 = *(const f32x4*)(qc + 12);
    }

    {
        unsigned* z0 = (unsigned*)bufA; unsigned* z1 = (unsigned*)bufB;
        #pragma unroll
        for (int i = 0; i < 16; ++i) { z0[tid + 256*i] = 0u; z1[tid + 256*i] = 0u; }
        const int c1 = tid >> 4, c2 = tid & 15;
        float m = 0.f;
        #pragma unroll
        for (int f = 0; f < 16; ++f) m += Wq[c1*16+f] * Wk[c2*16+f];
        Msh[c2*16 + c1] = m;
        if (tid < 16) {
            float wb = 0.f;
            #pragma unroll
            for (int g = 0; g < 16; ++g) wb += Wk[tid*16+g] * bq[g];
            wkbqSh[tid] = wb;
        }
        if (tid < 64) gSh[tid] = 0.f;
    }
    __syncthreads();

    W_DECL(Msh + rq*64);
    f32x4 wkb = *(const f32x4*)(wkbqSh + (f4 & 3)*4);

    f32x4 accS[4];
    #pragma unroll
    for (int nt = 0; nt < 4; ++nt) accS[nt] = (f32x4){0.f,0.f,0.f,0.f};

    for (int kc = 0; kc < NC; ++kc) {
        if (kc > 0) {
            const float* kp = kbase + kc*128 + f4*4;
            #pragma unroll
            for (int i = 0; i < 7; ++i) {
                const int t = t0 + 8*i; const int tc = t < 48 ? t : 48;
                kv[i] = *(const f32x4*)(kp + (size_t)tc*TOKS);
            }
            const float* qc = qbase + kc*128 + si*16 + (size_t)t0*TOKS;
            xa0 = *(const f32x4*)(qc);
            xa1 = *(const f32x4*)(qc + 4);
            xa2 = *(const f32x4*)(qc + 8);
            xa3 = *(const f32x4*)(qc + 12);
        }
        #pragma unroll
        for (int i = 0; i < 7; ++i) {
            const int t = t0 + 8*i;
            f32x4 xk = kv[i];
            if (t >= NT) xk = (f32x4){0.f,0.f,0.f,0.f};
            uint2 w; w.x = pk2(xk[0], xk[1]); w.y = pk2(xk[2], xk[3]);
            *(uint2*)((char*)bufB + ((t*256 + f4*8) ^ ((t & 7) << 4))) = w;
            const float pg = xk[0]*wkb[0] + xk[1]*wkb[1] + xk[2]*wkb[2] + xk[3]*wkb[3];
            if (pg != 0.f) atomicAdd(&gSh[t], pg);
        }
        #pragma unroll
        for (int i = 0; i < 7; ++i) {
            f32x4 xb0 = xa0, xb1 = xa1, xb2 = xa2, xb3 = xa3;
            if (i < 6) {
                const int tn = t0 + 8*(i+1); const int tc = tn < 48 ? tn : 48;
                const float* qc = qbase + kc*128 + si*16 + (size_t)tc*TOKS;
                xb0 = *(const f32x4*)(qc);
                xb1 = *(const f32x4*)(qc + 4);
                xb2 = *(const f32x4*)(qc + 8);
                xb3 = *(const f32x4*)(qc + 12);
            }
            const int t = t0 + 8*i;
            if (t < NT) {
                const float o0 = qdot(xa0,xa1,xa2,xa3, W00,W01,W02,W03);
                const float o1 = qdot(xa0,xa1,xa2,xa3, W10,W11,W12,W13);
                const float o2 = qdot(xa0,xa1,xa2,xa3, W20,W21,W22,W23);
                const float o3 = qdot(xa0,xa1,xa2,xa3, W30,W31,W32,W33);
                uint2 w; w.x = pk2(o0, o1); w.y = pk2(o2, o3);
                *(uint2*)((char*)bufA + ((t*256 + si*32 + rq*8) ^ ((t & 7) << 4))) = w;
            }
            xa0 = xb0; xa1 = xb1; xa2 = xb2; xa3 = xb3;
        }
        __syncthreads();
        #pragma unroll
        for (int ks = 0; ks < 4; ++ks) {
            const int ra  = wv*16 + (lane & 15);
            const int abo = (ra*256 + (ks*32 + (lane >> 4)*8)*2) ^ ((ra & 7) << 4);
            const bf16x8 af = *(const bf16x8*)((const char*)bufA + abo);
            #pragma unroll
            for (int nt = 0; nt < 4; ++nt) {
                const int rb  = nt*16 + (lane & 15);
                const int bbo = (rb*256 + (ks*32 + (lane >> 4)*8)*2) ^ ((rb & 7) << 4);
                const bf16x8 bf = *(const bf16x8*)((const char*)bufB + bbo);
                accS[nt] = __builtin_amdgcn_mfma_f32_16x16x32_bf16(af, bf, accS[nt], 0, 0, 0);
            }
        }
        if (kc + 1 < NC) __syncthreads();
    }

    float* slot = ws1 + (size_t)blockIdx.x * SLOT;
    #pragma unroll
    for (int nt = 0; nt < 4; ++nt) {
        const int col = nt*16 + (lane & 15);
        #pragma unroll
        for (int rr = 0; rr < 4; ++rr) {
            const int row = wv*16 + (lane >> 4)*4 + rr;
            if (row < NT) slot[row*64 + col] = accS[nt][rr];
        }
    }
    if (tid < 64) slot[3136 + tid] = gSh[tid];
}

// ===== K2: reduce + softmax, grid (b,h)=512, 256 thr =======================
template<int SPLIT>
__global__ __launch_bounds__(256, 2) void k_softmax(
    const float* __restrict__ ws1, float* __restrict__ attnp,
    ushort* __restrict__ ws2)
{
    __shared__ float sS[NT*69];
    __shared__ float sG[64];
    const int tid = threadIdx.x;
    const float* base = ws1 + (size_t)blockIdx.x * SPLIT * SLOT;

    for (int p = tid; p < 784; p += 256) {
        const int row = p >> 4, c4 = (p & 15) * 4;
        float4 acc = *(const float4*)(base + row*64 + c4);
        #pragma unroll
        for (int s = 1; s < SPLIT; ++s) {
            const float4 a = *(const float4*)(base + s*SLOT + row*64 + c4);
            acc.x += a.x; acc.y += a.y; acc.z += a.z; acc.w += a.w;
        }
        sS[row*69 + c4 + 0] = acc.x;
        sS[row*69 + c4 + 1] = acc.y;
        sS[row*69 + c4 + 2] = acc.z;
        sS[row*69 + c4 + 3] = acc.w;
    }
    if (tid < 64) {
        float g = base[3136 + tid];
        #pragma unroll
        for (int s = 1; s < SPLIT; ++s) g += base[s*SLOT + 3136 + tid];
        sG[tid] = g;
    }
    __syncthreads();

    if (tid < NT) {
        float mx = -1e30f;
        for (int j = 0; j < NT; ++j) {
            const float v = (sS[tid*69 + j] + sG[j]) * 0.03125f;
            sS[tid*69 + j] = v;
            mx = fmaxf(mx, v);
        }
        float ssum = 0.f;
        for (int j = 0; j < NT; ++j) {
            const float e = __expf(sS[tid*69 + j] - mx);
            sS[tid*69 + j] = e; ssum += e;
        }
        const float inv = 1.0f / ssum;
        for (int j = 0; j < NT; ++j) sS[tid*69 + j] *= inv;
    }
    __syncthreads();

    float* ab = attnp + (size_t)blockIdx.x * (NT*NT);
    for (int p = tid; p < NT*NT; p += 256) {
        const int t = p / NT, j = p - t*NT;
        ab[p] = sS[t*69 + j];
    }
    ushort* w2 = ws2 + (size_t)blockIdx.x * 4096;   // 64x64 bf16, zero-padded
    for (int p = tid; p < 4096; p += 256) {
        const int t = p >> 6, j = p & 63;
        const float v = (t < NT && j < NT) ? sS[t*69 + j] : 0.f;
        w2[p] = f2bf(v);
    }
}

// ===== K3: out = attn.Z + bvo, grid (b,h,kc)=4096, 256 thr =================
__global__ __launch_bounds__(256, 2) void k_out(
    const float* __restrict__ vin,
    const float* __restrict__ Wv, const float* __restrict__ bv,
    const float* __restrict__ Wo, const float* __restrict__ bo,
    const ushort* __restrict__ ws2, float* __restrict__ out)
{
    __shared__ unsigned Zt[4096];     // Z^T pair-packed: [128 n][32 kpair] u32
    __shared__ float WvoSh[256];      // (Wv Wo)^T
    __shared__ float bvoSh[16];

    const int tid  = threadIdx.x;
    const int lane = tid & 63;
    const int wv   = tid >> 6;        // 0..3 -> M-tile (token rows)
    const int kc   = blockIdx.x & 7;
    const int h    = (blockIdx.x >> 3) & 15;
    const int b    = blockIdx.x >> 7;
    const float* vbase = vin + (size_t)b*NT*TOKS + h*HSL;

    const int si = (tid >> 2) & 7;    // unit column group (invariant)
    const int rq = tid & 3;           // unit output quarter (invariant)
    const int t0 = tid >> 5;          // base token

    // ---- issue global loads first (attn A-fragments + v unit 0)
    const ushort* w2 = ws2 + ((size_t)(blockIdx.x >> 3)) * 4096;
    const int ra = wv*16 + (lane & 15);
    const bf16x8 af0 = *(const bf16x8*)(w2 + ra*64 +      (lane >> 4)*8);
    const bf16x8 af1 = *(const bf16x8*)(w2 + ra*64 + 32 + (lane >> 4)*8);
    f32x4 xa0, xa1, xa2, xa3;
    {
        const float* vc = vbase + kc*128 + si*16 + (size_t)t0*TOKS;
        xa0 = *(const f32x4*)(vc);
        xa1 = *(const f32x4*)(vc + 4);
        xa2 = *(const f32x4*)(vc + 8);
        xa3 = *(const f32x4*)(vc + 12);
    }

    {   // init: weights (transposed), bias, full Zt zero (covers t=49.. pad)
        const int c1 = tid >> 4, c2 = tid & 15;
        float wvo = 0.f;
        #pragma unroll
        for (int f = 0; f < 16; ++f) wvo += Wv[c1*16+f] * Wo[f*16+c2];
        WvoSh[c2*16 + c1] = wvo;                  // transposed store
        if (tid < 16) {
            float s2 = 0.f;
            #pragma unroll
            for (int g = 0; g < 16; ++g) s2 += bv[g]*Wo[g*16+tid];
            bvoSh[tid] = s2 + bo[tid];
        }
        #pragma unroll
        for (int i = 0; i < 16; ++i) Zt[tid + 256*i] = 0u;
    }
    __syncthreads();

    W_DECL(WvoSh + rq*64);
    const float bias = bvoSh[lane & 15];   // invariant: (n & 15) == lane & 15

    // ---- units: {load next, project current, 4 u16 writes into Zt}
    #pragma unroll
    for (int i = 0; i < 7; ++i) {
        f32x4 xb0 = xa0, xb1 = xa1, xb2 = xa2, xb3 = xa3;
        if (i < 6) {
            const int tn = t0 + 8*(i+1); const int tc = tn < 48 ? tn : 48;
            const float* vc = vbase + kc*128 + si*16 + (size_t)tc*TOKS;
            xb0 = *(const f32x4*)(vc);
            xb1 = *(const f32x4*)(vc + 4);
            xb2 = *(const f32x4*)(vc + 8);
            xb3 = *(const f32x4*)(vc + 12);
        }
        const int t = t0 + 8*i;
        if (t < NT) {
            const float o0 = qdot(xa0,xa1,xa2,xa3, W00,W01,W02,W03);
            const float o1 = qdot(xa0,xa1,xa2,xa3, W10,W11,W12,W13);
            const float o2 = qdot(xa0,xa1,xa2,xa3, W20,W21,W22,W23);
            const float o3 = qdot(xa0,xa1,xa2,xa3, W30,W31,W32,W33);
            const int n0 = si*16 + rq*4;
            const int pb = (t >> 1)*4, hb = (t & 1)*2;
            *(ushort*)((char*)Zt + ((((n0+0)*128 + pb) ^ ZSWZ(n0+0)) + hb)) = f2bf(o0);
            *(ushort*)((char*)Zt + ((((n0+1)*128 + pb) ^ ZSWZ(n0+1)) + hb)) = f2bf(o1);
            *(ushort*)((char*)Zt + ((((n0+2)*128 + pb) ^ ZSWZ(n0+2)) + hb)) = f2bf(o2);
            *(ushort*)((char*)Zt + ((((n0+3)*128 + pb) ^ ZSWZ(n0+3)) + hb)) = f2bf(o3);
        }
        xa0 = xb0; xa1 = xb1; xa2 = xb2; xa3 = xb3;
    }
    __syncthreads();

    // MFMA + direct global store (4 rows x 64B full sectors per instruction)
    float* obase = out + (size_t)b*NT*TOKS + h*HSL + kc*128;
    #pragma unroll
    for (int nt2 = 0; nt2 < 8; ++nt2) {
        const int n    = nt2*16 + (lane & 15);
        const int swzn = ZSWZ(n);
        const bf16x8 bf0 = *(const bf16x8*)((const char*)Zt + ((n*128 +      (lane >> 4)*16) ^ swzn));
        const bf16x8 bf1 = *(const bf16x8*)((const char*)Zt + ((n*128 + 64 + (lane >> 4)*16) ^ swzn));
        f32x4 acc = (f32x4){0.f, 0.f, 0.f, 0.f};
        acc = __builtin_amdgcn_mfma_f32_16x16x32_bf16(af0, bf0, acc, 0, 0, 0);
        acc = __builtin_amdgcn_mfma_f32_16x16x32_bf16(af1, bf1, acc, 0, 0, 0);
        #pragma unroll
        for (int r2 = 0; r2 < 4; ++r2) {
            const int row = wv*16 + (lane >> 4)*4 + r2;
            if (row < NT) obase[(size_t)row*TOKS + n] = acc[r2] + bias;
        }
    }
}

extern "C" void kernel_launch(void* const* d_in, const int* in_sizes, int n_in,
                              void* d_out, int out_size, void* d_ws, size_t ws_size,
                              hipStream_t stream) {
    const float* v  = (const float*)d_in[0];
    const float* k  = (const float*)d_in[1];
    const float* q  = (const float*)d_in[2];
    const float* Wq = (const float*)d_in[3];
    const float* bq = (const float*)d_in[4];
    const float* Wk = (const float*)d_in[5];
    const float* bk = (const float*)d_in[6];   // softmax-row-invariant; unused
    const float* Wv = (const float*)d_in[7];
    const float* bv = (const float*)d_in[8];
    const float* Wo = (const float*)d_in[9];
    const float* bo = (const float*)d_in[10];
    (void)bk; (void)in_sizes; (void)n_in; (void)out_size;

    float* outp  = (float*)d_out;
    float* attnp = outp + (size_t)32 * 49 * 16384;      // out | attn concat
    float* ws1   = (float*)d_ws;

    const size_t need8 = (size_t)4096*SLOT*4 + (size_t)512*4096*2;
    const size_t need4 = (size_t)2048*SLOT*4 + (size_t)512*4096*2;
    if (ws_size >= need8) {
        ushort* ws2 = (ushort*)(ws1 + (size_t)4096*SLOT);
        k_scores8    <<<dim3(4096), dim3(256), 0, stream>>>(q, k, Wq, bq, Wk, ws1);
        k_softmax<8> <<<dim3(512),  dim3(256), 0, stream>>>(ws1, attnp, ws2);
        k_out        <<<dim3(4096), dim3(256), 0, stream>>>(v, Wv, bv, Wo, bo, ws2, outp);
    } else if (ws_size >= need4) {
        ushort* ws2 = (ushort*)(ws1 + (size_t)2048*SLOT);
        k_scores<4,2><<<dim3(2048), dim3(256), 0, stream>>>(q, k, Wq, bq, Wk, ws1);
        k_softmax<4> <<<dim3(512),  dim3(256), 0, stream>>>(ws1, attnp, ws2);
        k_out        <<<dim3(4096), dim3(256), 0, stream>>>(v, Wv, bv, Wo, bo, ws2, outp);
    } else {
        ushort* ws2 = (ushort*)(ws1 + (size_t)1024*SLOT);
        k_scores<2,1><<<dim3(1024), dim3(256), 0, stream>>>(q, k, Wq, bq, Wk, ws1);
        k_softmax<2> <<<dim3(512),  dim3(256), 0, stream>>>(ws1, attnp, ws2);
        k_out        <<<dim3(4096), dim3(256), 0, stream>>>(v, Wv, bv, Wo, bo, ws2, outp);
    }
}